// Round 1
// baseline (699.974 us; speedup 1.0000x reference)
//
#include <hip/hip_runtime.h>
#include <stdint.h>

#define S_LEN 2048
#define BATCH 2
#define HIDDEN 2560
#define NH 8
#define NKV 4
#define HD 256
#define QSZ (NH*HD)          // 2048
#define NQKV 4096            // QSZ + 2*KVSZ
#define MROWS (BATCH*S_LEN)  // 4096
#define SCALE_ATT 0.0625f

using bf16x8 = __attribute__((__ext_vector_type__(8))) __bf16;
using f32x4  = __attribute__((__ext_vector_type__(4))) float;
using s16x8  = __attribute__((__ext_vector_type__(8))) short;

union B8u { s16x8 s; bf16x8 b; };

__device__ __forceinline__ unsigned short f2bf(float x){
  unsigned u = __float_as_uint(x);
  u += 0x7fffu + ((u >> 16) & 1u);
  return (unsigned short)(u >> 16);
}
__device__ __forceinline__ float bf2f(unsigned short h){
  return __uint_as_float(((unsigned)h) << 16);
}
__device__ __forceinline__ bf16x8 ld_bf8(const unsigned short* p){
  B8u u; u.s = *reinterpret_cast<const s16x8*>(p); return u.b;
}
__device__ __forceinline__ f32x4 mfma16(bf16x8 a, bf16x8 b, f32x4 c){
  return __builtin_amdgcn_mfma_f32_16x16x32_bf16(a, b, c, 0, 0, 0);
}
__device__ __forceinline__ void gload16(const void* g, void* l){
  __builtin_amdgcn_global_load_lds((const __attribute__((address_space(1))) void*)g,
                                   (__attribute__((address_space(3))) void*)l,
                                   16, 0, 0);
}

// ---------------- cast fp32 -> bf16 (flat) ----------------
__global__ __launch_bounds__(256) void cast_bf16_kernel(
    const float* __restrict__ in, unsigned short* __restrict__ out, int n)
{
  int i = (blockIdx.x * 256 + threadIdx.x) * 4;
  if (i < n){
    float4 v = *reinterpret_cast<const float4*>(in + i);
    ushort4 o;
    o.x = f2bf(v.x); o.y = f2bf(v.y); o.z = f2bf(v.z); o.w = f2bf(v.w);
    *reinterpret_cast<ushort4*>(out + i) = o;
  }
}

// ---------------- transpose + cast: in[R][C] fp32 -> out[C][R] bf16 ----------------
__global__ __launch_bounds__(256) void tcast_kernel(
    const float* __restrict__ in, unsigned short* __restrict__ out, int R, int C)
{
  __shared__ float t[32][33];
  int c0 = blockIdx.x * 32, r0 = blockIdx.y * 32;
  int tx = threadIdx.x & 31, ty = threadIdx.x >> 5;   // ty: 0..7
#pragma unroll
  for (int ii = 0; ii < 4; ii++)
    t[ty + ii*8][tx] = in[(size_t)(r0 + ty + ii*8) * C + c0 + tx];
  __syncthreads();
#pragma unroll
  for (int ii = 0; ii < 4; ii++)
    out[(size_t)(c0 + ty + ii*8) * R + r0 + tx] = f2bf(t[tx][ty + ii*8]);
}

// ---------------- bf16 MFMA GEMM: C[M][N] f32 = A[M][K] * BT[N][K]^T ----------------
// 128x128 tile, BK=32, 4 waves (2x2), 4x4 16x16 frags per wave, global_load_lds w=16.
__global__ __launch_bounds__(256) void gemm_bt_kernel(
    const unsigned short* __restrict__ A,
    const unsigned short* __restrict__ BT,
    float* __restrict__ C,
    int M, int N, int K)
{
  __shared__ unsigned short As[128 * 32];
  __shared__ unsigned short Bs[128 * 32];
  const int tid  = threadIdx.x;
  const int lane = tid & 63;
  const int wid  = tid >> 6;
  const int bm = blockIdx.y, bn = blockIdx.x;
  const int wm = wid >> 1, wn = wid & 1;
  const int lq = lane & 15, lk = lane >> 4;

  f32x4 acc[4][4] = {};

  // staging: chunk q of wave w covers lds bytes [w*2048 + q*1024, +1024), lane writes +lane*16
  // -> row = w*32 + q*16 + lane/4, col elems = (lane&3)*8
  const int srow = wid * 32 + (lane >> 2);
  const int scol = (lane & 3) * 8;
  const unsigned short* ag0 = A  + (size_t)(bm*128 + srow     ) * K + scol;
  const unsigned short* ag1 = A  + (size_t)(bm*128 + srow + 16) * K + scol;
  const unsigned short* bg0 = BT + (size_t)(bn*128 + srow     ) * K + scol;
  const unsigned short* bg1 = BT + (size_t)(bn*128 + srow + 16) * K + scol;
  unsigned short* as0 = As + wid * 1024;
  unsigned short* as1 = As + wid * 1024 + 512;
  unsigned short* bs0 = Bs + wid * 1024;
  unsigned short* bs1 = Bs + wid * 1024 + 512;

  const unsigned short* ap = As + (wm*64 + lq) * 32 + lk * 8;
  const unsigned short* bp = Bs + (wn*64 + lq) * 32 + lk * 8;

  for (int k0 = 0; k0 < K; k0 += 32){
    __syncthreads();                    // all waves done reading previous tile
    gload16(ag0, as0); gload16(ag1, as1);
    gload16(bg0, bs0); gload16(bg1, bs1);
    ag0 += 32; ag1 += 32; bg0 += 32; bg1 += 32;
    __syncthreads();                    // staged data visible (vmcnt drained)
    bf16x8 af[4], bfv[4];
#pragma unroll
    for (int i = 0; i < 4; i++){
      af[i]  = ld_bf8(ap + i * 512);    // 16 rows * 32 cols
      bfv[i] = ld_bf8(bp + i * 512);
    }
#pragma unroll
    for (int mm = 0; mm < 4; mm++)
#pragma unroll
      for (int nn = 0; nn < 4; nn++)
        acc[mm][nn] = mfma16(af[mm], bfv[nn], acc[mm][nn]);
  }

  const int r0 = bm*128 + wm*64, c0 = bn*128 + wn*64;
#pragma unroll
  for (int mm = 0; mm < 4; mm++)
#pragma unroll
    for (int nn = 0; nn < 4; nn++)
#pragma unroll
      for (int i = 0; i < 4; i++)
        C[(size_t)(r0 + mm*16 + lk*4 + i) * N + (c0 + nn*16 + lq)] = acc[mm][nn][i];
}

// ---------------- RMSNorm + RoPE + scatter to q/k/vT ----------------
// qkv fp32 [MROWS][4096]; q -> [B][NH][S][HD] bf16, k -> [B][NKV][S][HD] bf16,
// v -> transposed [B][NKV][HD][S] bf16.
__global__ __launch_bounds__(256) void normrope_kernel(
    const float* __restrict__ qkv,
    const int* __restrict__ positions,
    const float* __restrict__ qw, const float* __restrict__ kw,
    unsigned short* __restrict__ qB,
    unsigned short* __restrict__ kB,
    unsigned short* __restrict__ vT)
{
  const int s = blockIdx.x, b = blockIdx.y;
  const int lane = threadIdx.x & 63, wid = threadIdx.x >> 6;
  const float* row = qkv + (size_t)(b * S_LEN + s) * NQKV;
  const float fpos = (float)positions[b * S_LEN + s];

#pragma unroll
  for (int t = 0; t < 4; t++){
    const int seg = t * 4 + wid;         // 0..7 q heads, 8..11 k heads, 12..15 v heads
    const int base = seg * HD;
    float x0 = row[base + lane];
    float x1 = row[base + lane + 64];
    float x2 = row[base + lane + 128];
    float x3 = row[base + lane + 192];
    if (seg >= 12){
      const int mh = seg - 12;
      unsigned short* vb = vT + (size_t)(b * NKV + mh) * HD * S_LEN + s;
      vb[(size_t)(lane      ) * S_LEN] = f2bf(x0);
      vb[(size_t)(lane +  64) * S_LEN] = f2bf(x1);
      vb[(size_t)(lane + 128) * S_LEN] = f2bf(x2);
      vb[(size_t)(lane + 192) * S_LEN] = f2bf(x3);
    } else {
      const float* w = (seg < 8) ? qw : kw;
      float ssq = x0*x0 + x1*x1 + x2*x2 + x3*x3;
#pragma unroll
      for (int d = 1; d < 64; d <<= 1) ssq += __shfl_xor(ssq, d, 64);
      float rs = rsqrtf(ssq * (1.0f / 256.0f) + 1e-6f);
      float y0 = x0 * rs * (1.0f + w[lane]);
      float y1 = x1 * rs * (1.0f + w[lane + 64]);
      float y2 = x2 * rs * (1.0f + w[lane + 128]);
      float y3 = x3 * rs * (1.0f + w[lane + 192]);
      // rope: pair p uses (x[p], x[p+128]); this lane owns p=lane and p=lane+64
      const float kln = -9.210340371976184f / 128.0f;   // -ln(10000)/128
      float inv1 = expf((float)lane * kln);
      float inv2 = expf((float)(lane + 64) * kln);
      float s1, c1, s2, c2;
      sincosf(fpos * inv1, &s1, &c1);
      sincosf(fpos * inv2, &s2, &c2);
      float o0 = y0 * c1 - y2 * s1;
      float o2 = y2 * c1 + y0 * s1;
      float o1 = y1 * c2 - y3 * s2;
      float o3 = y3 * c2 + y1 * s2;
      unsigned short* dst = (seg < 8)
        ? qB + ((size_t)(b * NH  +  seg     ) * S_LEN + s) * HD
        : kB + ((size_t)(b * NKV + (seg - 8)) * S_LEN + s) * HD;
      dst[lane      ] = f2bf(o0);
      dst[lane +  64] = f2bf(o1);
      dst[lane + 128] = f2bf(o2);
      dst[lane + 192] = f2bf(o3);
    }
  }
}

// ---------------- flash attention (full causal), 1 wave = 16 queries ----------------
__global__ __launch_bounds__(256) void attn_kernel(
    const unsigned short* __restrict__ qB,
    const unsigned short* __restrict__ kB,
    const unsigned short* __restrict__ vT,
    const int* __restrict__ amask,
    unsigned short* __restrict__ attnO)
{
  __shared__ unsigned short p_lds[4][16][40];   // per-wave P buffer, padded rows (80B)
  const int lane = threadIdx.x & 63, wid = threadIdx.x >> 6;
  const int h = blockIdx.y, b = blockIdx.z;
  const int qt = gridDim.x - 1 - blockIdx.x;    // heavy tiles first
  const int q0 = qt * 64 + wid * 16;
  const int mh = h >> 1;                        // NH/NKV = 2
  const int lq = lane & 15, lk = lane >> 4;

  // Q fragments: row = q0+lq, 8 k-slices of 32
  const unsigned short* qbase = qB + ((size_t)(b * NH + h) * S_LEN + q0 + lq) * HD + lk * 8;
  bf16x8 aq[8];
#pragma unroll
  for (int ks = 0; ks < 8; ks++) aq[ks] = ld_bf8(qbase + ks * 32);

  float mi[4] = {-__builtin_inff(), -__builtin_inff(), -__builtin_inff(), -__builtin_inff()};
  float li[4] = {0.f, 0.f, 0.f, 0.f};
  f32x4 oacc[16] = {};

  const unsigned short* kbase = kB + (size_t)(b * NKV + mh) * S_LEN * HD;
  const unsigned short* vbase = vT + (size_t)(b * NKV + mh) * HD * S_LEN;
  const int* am = amask + b * S_LEN;
  const int ktend = (q0 + 15) & ~31;

  for (int kt = 0; kt <= ktend; kt += 32){
    f32x4 s0 = {0.f,0.f,0.f,0.f}, s1 = {0.f,0.f,0.f,0.f};
    const unsigned short* kp0 = kbase + (size_t)(kt + lq) * HD + lk * 8;
    const unsigned short* kp1 = kp0 + 16 * HD;
#pragma unroll
    for (int ks = 0; ks < 8; ks++){
      bf16x8 kf0 = ld_bf8(kp0 + ks * 32);
      bf16x8 kf1 = ld_bf8(kp1 + ks * 32);
      s0 = mfma16(aq[ks], kf0, s0);
      s1 = mfma16(aq[ks], kf1, s1);
    }
    const int key0 = kt + lq, key1 = kt + 16 + lq;
    const bool ok0 = (am[key0] != 0), ok1 = (am[key1] != 0);
    float alpha[4];
#pragma unroll
    for (int i = 0; i < 4; i++){
      const int q = q0 + lk * 4 + i;
      float v0 = (key0 <= q && ok0) ? s0[i] * SCALE_ATT : -__builtin_inff();
      float v1 = (key1 <= q && ok1) ? s1[i] * SCALE_ATT : -__builtin_inff();
      float tm = fmaxf(v0, v1);
      tm = fmaxf(tm, __shfl_xor(tm, 1, 64));
      tm = fmaxf(tm, __shfl_xor(tm, 2, 64));
      tm = fmaxf(tm, __shfl_xor(tm, 4, 64));
      tm = fmaxf(tm, __shfl_xor(tm, 8, 64));
      float mn  = fmaxf(mi[i], tm);
      float mns = fmaxf(mn, -1e30f);    // -inf-safe exponent base
      float p0 = __expf(v0 - mns);
      float p1 = __expf(v1 - mns);
      float a_ = __expf(mi[i] - mns);
      float rsum = p0 + p1;
      rsum += __shfl_xor(rsum, 1, 64);
      rsum += __shfl_xor(rsum, 2, 64);
      rsum += __shfl_xor(rsum, 4, 64);
      rsum += __shfl_xor(rsum, 8, 64);
      li[i] = li[i] * a_ + rsum;
      mi[i] = mn;
      alpha[i] = a_;
      p_lds[wid][lk*4 + i][lq]      = f2bf(p0);
      p_lds[wid][lk*4 + i][lq + 16] = f2bf(p1);
    }
#pragma unroll
    for (int db = 0; db < 16; db++){
      f32x4 o = oacc[db];
#pragma unroll
      for (int i = 0; i < 4; i++) o[i] *= alpha[i];
      oacc[db] = o;
    }
    asm volatile("s_waitcnt lgkmcnt(0)" ::: "memory");
    bf16x8 pa = ld_bf8(&p_lds[wid][lq][lk * 8]);   // P row lq, keys lk*8..+7
    const unsigned short* vp = vbase + (size_t)lq * S_LEN + kt + lk * 8;
#pragma unroll
    for (int db = 0; db < 16; db++){
      bf16x8 vf = ld_bf8(vp + (size_t)db * 16 * S_LEN);
      oacc[db] = mfma16(pa, vf, oacc[db]);
    }
  }

#pragma unroll
  for (int i = 0; i < 4; i++){
    float inv = 1.0f / li[i];
    unsigned short* orow = attnO + (size_t)(b * S_LEN + q0 + lk*4 + i) * QSZ + h * HD + lq;
#pragma unroll
    for (int db = 0; db < 16; db++)
      orow[db * 16] = f2bf(oacc[db][i] * inv);
  }
}

extern "C" void kernel_launch(void* const* d_in, const int* in_sizes, int n_in,
                              void* d_out, int out_size, void* d_ws, size_t ws_size,
                              hipStream_t stream)
{
  const int*   positions = (const int*)  d_in[0];
  const float* hidden    = (const float*)d_in[1];
  const int*   amask     = (const int*)  d_in[2];
  const float* Wqkv      = (const float*)d_in[3];
  const float* Wo        = (const float*)d_in[4];
  const float* qw        = (const float*)d_in[5];
  const float* kw        = (const float*)d_in[6];
  float* out = (float*)d_out;

  char* ws = (char*)d_ws;
  unsigned short* hB    = (unsigned short*)(ws);               // 4096x2560 bf16 (20.97MB)
  unsigned short* attnO = (unsigned short*)(ws);               // alias (4096x2048 bf16, after GEMM1)
  unsigned short* WqT   = (unsigned short*)(ws + 20971520);    // [4096][2560] bf16
  unsigned short* WoT   = (unsigned short*)(ws + 41943040);    // [2560][2048] bf16
  float*          qkvF  = (float*)        (ws + 52428800);    // [4096][4096] f32
  unsigned short* qb    = (unsigned short*)(ws + 119537664);   // [B][NH][S][HD]
  unsigned short* kb    = (unsigned short*)(ws + 136314880);   // [B][NKV][S][HD]
  unsigned short* vt    = (unsigned short*)(ws + 144703488);   // [B][NKV][HD][S]

  cast_bf16_kernel<<<dim3(MROWS * HIDDEN / 1024), 256, 0, stream>>>(hidden, hB, MROWS * HIDDEN);
  tcast_kernel<<<dim3(NQKV / 32, HIDDEN / 32), 256, 0, stream>>>(Wqkv, WqT, HIDDEN, NQKV);
  tcast_kernel<<<dim3(HIDDEN / 32, QSZ / 32), 256, 0, stream>>>(Wo, WoT, QSZ, HIDDEN);

  gemm_bt_kernel<<<dim3(NQKV / 128, MROWS / 128), 256, 0, stream>>>(hB, WqT, qkvF, MROWS, NQKV, HIDDEN);

  normrope_kernel<<<dim3(S_LEN, BATCH), 256, 0, stream>>>(qkvF, positions, qw, kw, qb, kb, vt);

  attn_kernel<<<dim3(S_LEN / 64, NH, BATCH), 256, 0, stream>>>(qb, kb, vt, amask, attnO);

  gemm_bt_kernel<<<dim3(HIDDEN / 128, MROWS / 128), 256, 0, stream>>>(attnO, WoT, out, MROWS, HIDDEN, QSZ);
}